// Round 8
// baseline (387.356 us; speedup 1.0000x reference)
//
#include <hip/hip_runtime.h>

typedef _Float16 half_t;
typedef __attribute__((ext_vector_type(8))) _Float16 half8;

#define DIM 96
#define NBINS 64
#define BSZ 15
#define PADROWS (DIM + BSZ - 1)   /* 110 */
#define NTHREADS 256
#define RS_F 68                   /* f32 LDS row stride in floats (64+4 pad) */
#define RS4_F 17                  /* same, in float4 */
#define TY 8                      /* out rows per block in fused kernel */
#define YTILES (DIM / TY)         /* 12 */
#define TZ 12                     /* z rows per block in z-stream kernel */
#define ZTILES (DIM / TZ)         /* 8 */
#define ROWE (DIM * NBINS)        /* 6144 elements per (z,y) row */
#define TPE 24                    /* elements per thread in z-stream (6144/256) */

// ===========================================================================
// Gradient + faithful soft-binning of voxel (z,y,x) scatter-added (sgn=+1)
// or -subtracted (sgn=-1) into plane row V[x*RS_F + bin]. Lane x touches
// ONLY row x of its plane -> race-free without atomics.
// ===========================================================================
__device__ __forceinline__ void bin_line_scatter(
    const float* __restrict__ in, float* __restrict__ V,
    const int y, const int z, const int x, const float sgn)
{
    if (x < DIM) {
        const int idx = (z * DIM + y) * DIM + x;
        const float xm = (x > 0)       ? in[idx - 1]         : 0.0f;
        const float xp = (x < DIM - 1) ? in[idx + 1]         : 0.0f;
        const float ym = (y > 0)       ? in[idx - DIM]       : 0.0f;
        const float yp = (y < DIM - 1) ? in[idx + DIM]       : 0.0f;
        const float zm = (z > 0)       ? in[idx - DIM * DIM] : 0.0f;
        const float zp = (z < DIM - 1) ? in[idx + DIM * DIM] : 0.0f;
        const float gx = xp - xm, gy = yp - ym, gz = zp - zm;

        const float EPSF  = 2.220446049250313e-16f;
        const float TWOPI = 6.28318530717958647692f;
        const float PIF   = 3.14159265358979323846f;

        const float r = sqrtf(gx * gx + gy * gy + gz * gz);
        float theta = atanf(gy / (gx + EPSF));
        const float phi = acosf(gz / (r + EPSF));
        if (theta < 0.0f) theta += TWOPI;
        const float t_raw = theta / (TWOPI / 8.0f);
        const float p_raw = phi   / (PIF   / 8.0f);
        const float ft = floorf(t_raw);
        const float fp = floorf(p_raw);
        int lt = (int)ft; if (lt == 8) lt = 0;
        int lp = (int)fp; if (lp == 8) lp = 0;
        const int ht = (lt + 1) & 7;
        const int hp = (lp + 1) & 7;
        const float frac  = t_raw - ft;
        const float w_lo  = fminf(frac, 1.0f - frac);
        const float w_hi  = 1.0f - w_lo;
        const float wp_lo = (frac == 0.0f) ? 1.0f : w_lo;  // faithful: theta frac gates phi split
        const float wp_hi = 1.0f - wp_lo;

        const float rs = r * sgn;
        float* vrow = V + x * RS_F;
        vrow[lt * 8 + lp] += rs * w_lo * wp_lo;
        vrow[ht * 8 + lp] += rs * w_hi * wp_lo;
        vrow[lt * 8 + hp] += rs * w_lo * wp_hi;
        vrow[ht * 8 + hp] += rs * w_hi * wp_hi;
    }
}

// ===========================================================================
// KA2: fused bin + x-window + y-window -> fp16 ws1[z][y][x][64].
// Dual accumulator planes: group 0 (tid<128) scatters into A, group 1 into B.
// Effective sum = A + B (read-combined). Prologue: 14 lines in 7 dual steps
// (evens->A, odds->B). Steady row y: g0 adds +line(y+14) to A while g1 adds
// -line(y-1) to B. Net visible sum at read = lines [y, y+14]. Deterministic.
// ===========================================================================
__global__ __launch_bounds__(NTHREADS) void kA2_bin_xy_h(
    const float* __restrict__ in, half_t* __restrict__ ws1)
{
    __shared__ float A[PADROWS * RS_F];
    __shared__ float B[PADROWS * RS_F];
    const int tid = threadIdx.x;
    const int y0 = blockIdx.x * TY;
    const int z  = blockIdx.y;

    for (int i = tid; i < PADROWS * RS4_F; i += NTHREADS) {
        ((float4*)A)[i] = make_float4(0.f, 0.f, 0.f, 0.f);
        ((float4*)B)[i] = make_float4(0.f, 0.f, 0.f, 0.f);
    }
    __syncthreads();

    const int g = tid >> 7;              // 0: plane A, 1: plane B
    const int l = tid & 127;             // lane within group (x if < 96)
    float* P = g ? B : A;

    // prologue: lines y0..y0+13 in 7 dual steps (guarded vs y >= DIM)
    #pragma unroll
    for (int k = 0; k < (BSZ - 1) / 2; ++k) {
        const int ys = y0 + 2 * k + g;
        if (ys < DIM) bin_line_scatter(in, P, ys, z, l, 1.0f);
    }

    const int c8 = tid & 7;              // 8 bins (one half8)
    const int strip = tid >> 3;          // 0..31, 3 positions each
    const int pos0 = strip * 3;
    const float4* A4 = (const float4*)A;
    const float4* B4 = (const float4*)B;

    for (int r = 0; r < TY; ++r) {
        const int y = y0 + r;
        // concurrent dual scatter (disjoint planes)
        if (g == 0) {
            if (y + BSZ - 1 < DIM) bin_line_scatter(in, A, y + BSZ - 1, z, l, 1.0f);
        } else {
            if (r >= 1) bin_line_scatter(in, B, y - 1, z, l, -1.0f);
        }
        __syncthreads();                 // planes complete for row y

        // x-window of (A+B) via running window over pos0..pos0+2
        float acc[8];
        #pragma unroll
        for (int k = 0; k < 8; ++k) acc[k] = 0.f;
        #pragma unroll
        for (int d = 0; d < BSZ; ++d) {
            const int ri = (pos0 + d) * RS4_F + c8 * 2;
            const float4 a  = A4[ri],     b  = A4[ri + 1];
            const float4 a2 = B4[ri],     b2 = B4[ri + 1];
            acc[0] += a.x + a2.x; acc[1] += a.y + a2.y;
            acc[2] += a.z + a2.z; acc[3] += a.w + a2.w;
            acc[4] += b.x + b2.x; acc[5] += b.y + b2.y;
            acc[6] += b.z + b2.z; acc[7] += b.w + b2.w;
        }
        int pos = pos0;
        #pragma unroll
        for (int j = 0; j < 3; ++j) {
            half8 o;
            #pragma unroll
            for (int k = 0; k < 8; ++k) o[k] = (half_t)acc[k];
            *(half8*)(ws1 + (((size_t)(z * DIM + y) * DIM + pos) * NBINS + c8 * 8)) = o;
            if (j < 2) {
                const int r0 = pos * RS4_F + c8 * 2;
                const int r1 = (pos + BSZ) * RS4_F + c8 * 2;
                const float4 a0 = A4[r0], b0 = A4[r0 + 1];
                const float4 c0 = B4[r0], d0 = B4[r0 + 1];
                const float4 a1 = A4[r1], b1 = A4[r1 + 1];
                const float4 c1 = B4[r1], d1 = B4[r1 + 1];
                acc[0] += (a1.x + c1.x) - (a0.x + c0.x);
                acc[1] += (a1.y + c1.y) - (a0.y + c0.y);
                acc[2] += (a1.z + c1.z) - (a0.z + c0.z);
                acc[3] += (a1.w + c1.w) - (a0.w + c0.w);
                acc[4] += (b1.x + d1.x) - (b0.x + d0.x);
                acc[5] += (b1.y + d1.y) - (b0.y + d0.y);
                acc[6] += (b1.z + d1.z) - (b0.z + d0.z);
                acc[7] += (b1.w + d1.w) - (b0.w + d0.w);
                ++pos;
            }
        }
        __syncthreads();                 // all reads done before next scatter
    }
}

// ===========================================================================
// K3S: z-window, fp16 ws1 -> f32 out, PURE CONTIGUOUS STREAMING.
// Block = (y, z-tile of TZ). Thread t owns elements [t*24, t*24+24) of every
// (z,y) row (6144 elems). Running window in 24 f32 registers; every global
// access is a block-wide contiguous 12KB read / 24KB write. No LDS/barriers.
// ===========================================================================
__global__ __launch_bounds__(NTHREADS) void k3_zstream_h(
    const half_t* __restrict__ ws1, float* __restrict__ out)
{
    const int tid = threadIdx.x;
    const int y  = blockIdx.x;
    const int z0 = blockIdx.y * TZ;
    const int off = tid * TPE;

    float acc[TPE];
    #pragma unroll
    for (int e = 0; e < TPE; ++e) acc[e] = 0.f;

    // prologue: rows z0..z0+13 (guarded)
    #pragma unroll
    for (int d = 0; d < BSZ - 1; ++d) {
        const int zz = z0 + d;
        if (zz < DIM) {
            const half_t* p = ws1 + (size_t)(zz * DIM + y) * ROWE + off;
            const half8 h0 = *(const half8*)(p);
            const half8 h1 = *(const half8*)(p + 8);
            const half8 h2 = *(const half8*)(p + 16);
            #pragma unroll
            for (int e = 0; e < 8; ++e) {
                acc[e]      += (float)h0[e];
                acc[8 + e]  += (float)h1[e];
                acc[16 + e] += (float)h2[e];
            }
        }
    }

    for (int i = 0; i < TZ; ++i) {
        const int z = z0 + i;
        if (z + BSZ - 1 < DIM) {
            const half_t* p = ws1 + (size_t)((z + BSZ - 1) * DIM + y) * ROWE + off;
            const half8 h0 = *(const half8*)(p);
            const half8 h1 = *(const half8*)(p + 8);
            const half8 h2 = *(const half8*)(p + 16);
            #pragma unroll
            for (int e = 0; e < 8; ++e) {
                acc[e]      += (float)h0[e];
                acc[8 + e]  += (float)h1[e];
                acc[16 + e] += (float)h2[e];
            }
        }
        float4* op = (float4*)(out + (size_t)(z * DIM + y) * ROWE + off);
        #pragma unroll
        for (int q = 0; q < TPE / 4; ++q)
            op[q] = make_float4(acc[4 * q], acc[4 * q + 1], acc[4 * q + 2], acc[4 * q + 3]);
        if (i < TZ - 1) {
            const half_t* p = ws1 + (size_t)(z * DIM + y) * ROWE + off;   // L2-warm
            const half8 h0 = *(const half8*)(p);
            const half8 h1 = *(const half8*)(p + 8);
            const half8 h2 = *(const half8*)(p + 16);
            #pragma unroll
            for (int e = 0; e < 8; ++e) {
                acc[e]      -= (float)h0[e];
                acc[8 + e]  -= (float)h1[e];
                acc[16 + e] -= (float)h2[e];
            }
        }
    }
}

// ===========================================================================
// Fallback (ws too small): R3/R6 f32 path, in place on out.
// ===========================================================================
__global__ __launch_bounds__(NTHREADS) void k1_bin_xsum_f(
    const float* __restrict__ in, float* __restrict__ out)
{
    __shared__ float V[PADROWS * RS_F];
    const int tid = threadIdx.x;
    const int y = blockIdx.x, z = blockIdx.y;

    for (int i = tid; i < PADROWS * RS4_F; i += NTHREADS)
        ((float4*)V)[i] = make_float4(0.f, 0.f, 0.f, 0.f);
    __syncthreads();
    bin_line_scatter(in, V, y, z, tid, 1.0f);
    __syncthreads();

    const int c4 = tid & 15;
    const int strip = tid >> 4;
    int pos = strip * 6;
    const float4* V4 = (const float4*)V;

    float4 s = make_float4(0.f, 0.f, 0.f, 0.f);
    #pragma unroll
    for (int d = 0; d < BSZ; ++d) {
        const float4 v = V4[(pos + d) * RS4_F + c4];
        s.x += v.x; s.y += v.y; s.z += v.z; s.w += v.w;
    }
    float4* out4 = (float4*)out;
    const int base = (z * DIM + y) * DIM * 16;
    out4[base + pos * 16 + c4] = s;
    #pragma unroll
    for (int j = 1; j < 6; ++j) {
        const float4 a = V4[pos * RS4_F + c4];
        const float4 b = V4[(pos + BSZ) * RS4_F + c4];
        s.x += b.x - a.x; s.y += b.y - a.y; s.z += b.z - a.z; s.w += b.w - a.w;
        ++pos;
        out4[base + pos * 16 + c4] = s;
    }
}

__global__ __launch_bounds__(NTHREADS) void k_axis_sum_f(
    float* __restrict__ data, const int mulY, const int stride4)
{
    __shared__ float4 V4[PADROWS * RS4_F];
    const int tid = threadIdx.x;
    const int base4 = (blockIdx.y * mulY + blockIdx.x) * 16;
    float4* data4 = (float4*)data;

    for (int i = tid; i < DIM * 16; i += NTHREADS) {
        const int pos = i >> 4, c4 = i & 15;
        V4[pos * RS4_F + c4] = data4[base4 + (size_t)pos * stride4 + c4];
    }
    for (int i = tid; i < (PADROWS - DIM) * 16; i += NTHREADS) {
        const int pos = DIM + (i >> 4), c4 = i & 15;
        V4[pos * RS4_F + c4] = make_float4(0.f, 0.f, 0.f, 0.f);
    }
    __syncthreads();

    const int c4 = tid & 15;
    const int strip = tid >> 4;
    int pos = strip * 6;

    float4 s = make_float4(0.f, 0.f, 0.f, 0.f);
    #pragma unroll
    for (int d = 0; d < BSZ; ++d) {
        const float4 v = V4[(pos + d) * RS4_F + c4];
        s.x += v.x; s.y += v.y; s.z += v.z; s.w += v.w;
    }
    data4[base4 + (size_t)pos * stride4 + c4] = s;
    #pragma unroll
    for (int j = 1; j < 6; ++j) {
        const float4 a = V4[pos * RS4_F + c4];
        const float4 b = V4[(pos + BSZ) * RS4_F + c4];
        s.x += b.x - a.x; s.y += b.y - a.y; s.z += b.z - a.z; s.w += b.w - a.w;
        ++pos;
        data4[base4 + (size_t)pos * stride4 + c4] = s;
    }
}

extern "C" void kernel_launch(void* const* d_in, const int* in_sizes, int n_in,
                              void* d_out, int out_size, void* d_ws, size_t ws_size,
                              hipStream_t stream) {
    (void)in_sizes; (void)n_in; (void)out_size;
    const float* x = (const float*)d_in[0];
    float* out = (float*)d_out;
    const size_t nvox = (size_t)DIM * DIM * DIM * NBINS;   // 56,623,104
    const size_t need = nvox * sizeof(half_t);             // 113.2 MB

    dim3 block(NTHREADS);
    if (ws_size >= need) {
        half_t* ws1 = (half_t*)d_ws;
        // Fused bin + x-window + y-window -> ws1 (fp16)
        kA2_bin_xy_h<<<dim3(YTILES, DIM), block, 0, stream>>>(x, ws1);
        // z-window -> out (f32), contiguous streaming
        k3_zstream_h<<<dim3(DIM, ZTILES), block, 0, stream>>>(ws1, out);
    } else {
        k1_bin_xsum_f<<<dim3(DIM, DIM), block, 0, stream>>>(x, out);
        k_axis_sum_f<<<dim3(DIM, DIM), block, 0, stream>>>(out, DIM * DIM * 16, DIM * 16);
        k_axis_sum_f<<<dim3(DIM, DIM), block, 0, stream>>>(out, DIM * 16, DIM * DIM * 16);
    }
}

// Round 10
// 341.741 us; speedup vs baseline: 1.1335x; 1.1335x over previous
//
#include <hip/hip_runtime.h>

typedef _Float16 half_t;
typedef __attribute__((ext_vector_type(8))) _Float16 half8;

#define DIM 96
#define NBINS 64
#define BSZ 15
#define PADROWS (DIM + BSZ - 1)   /* 110 */
#define NTHREADS 256
#define RS_F 68                   /* f32 LDS row stride in floats (64+4 pad) */
#define RS4_F 17                  /* same, in float4 */
#define TY 4                      /* out rows per block in fused kernel */
#define YTILES (DIM / TY)         /* 24 */
#define TZ 12                     /* z rows per block in z-stream kernel */
#define ZTILES (DIM / TZ)         /* 8 */
#define ROWE (DIM * NBINS)        /* 6144 elements per (z,y) row */

// ===========================================================================
// Gradient + faithful soft-binning of voxel (z,y,x) scatter-added (sgn=+1)
// or -subtracted (sgn=-1) into LDS row V[x*RS_F + bin]. Lane x touches ONLY
// row x -> race-free, no barrier needed for the scatter itself.
// ===========================================================================
__device__ __forceinline__ void bin_line_scatter(
    const float* __restrict__ in, float* __restrict__ V,
    const int y, const int z, const int x, const float sgn)
{
    if (x < DIM) {
        const int idx = (z * DIM + y) * DIM + x;
        const float xm = (x > 0)       ? in[idx - 1]         : 0.0f;
        const float xp = (x < DIM - 1) ? in[idx + 1]         : 0.0f;
        const float ym = (y > 0)       ? in[idx - DIM]       : 0.0f;
        const float yp = (y < DIM - 1) ? in[idx + DIM]       : 0.0f;
        const float zm = (z > 0)       ? in[idx - DIM * DIM] : 0.0f;
        const float zp = (z < DIM - 1) ? in[idx + DIM * DIM] : 0.0f;
        const float gx = xp - xm, gy = yp - ym, gz = zp - zm;

        const float EPSF  = 2.220446049250313e-16f;
        const float TWOPI = 6.28318530717958647692f;
        const float PIF   = 3.14159265358979323846f;

        const float r = sqrtf(gx * gx + gy * gy + gz * gz);
        float theta = atanf(gy / (gx + EPSF));
        const float phi = acosf(gz / (r + EPSF));
        if (theta < 0.0f) theta += TWOPI;
        const float t_raw = theta / (TWOPI / 8.0f);
        const float p_raw = phi   / (PIF   / 8.0f);
        const float ft = floorf(t_raw);
        const float fp = floorf(p_raw);
        int lt = (int)ft; if (lt == 8) lt = 0;
        int lp = (int)fp; if (lp == 8) lp = 0;
        const int ht = (lt + 1) & 7;
        const int hp = (lp + 1) & 7;
        const float frac  = t_raw - ft;
        const float w_lo  = fminf(frac, 1.0f - frac);
        const float w_hi  = 1.0f - w_lo;
        const float wp_lo = (frac == 0.0f) ? 1.0f : w_lo;  // faithful: theta frac gates phi split
        const float wp_hi = 1.0f - wp_lo;

        const float rs = r * sgn;
        float* vrow = V + x * RS_F;
        vrow[lt * 8 + lp] += rs * w_lo * wp_lo;
        vrow[ht * 8 + lp] += rs * w_hi * wp_lo;
        vrow[lt * 8 + hp] += rs * w_lo * wp_hi;
        vrow[ht * 8 + hp] += rs * w_hi * wp_hi;
    }
}

// ===========================================================================
// KA: fused bin + x-window + y-window -> fp16 ws1[z][y][x][64].
// (R7 version, verbatim: single plane, TY=4, best known.)
// ===========================================================================
__global__ __launch_bounds__(NTHREADS) void kA_bin_xy_h(
    const float* __restrict__ in, half_t* __restrict__ ws1)
{
    __shared__ float V[PADROWS * RS_F];
    const int tid = threadIdx.x;
    const int y0 = blockIdx.x * TY;
    const int z  = blockIdx.y;

    for (int i = tid; i < PADROWS * RS4_F; i += NTHREADS)
        ((float4*)V)[i] = make_float4(0.f, 0.f, 0.f, 0.f);
    __syncthreads();

    #pragma unroll
    for (int j = 0; j < BSZ - 1; ++j) {
        const int ys = y0 + j;
        if (ys < DIM) bin_line_scatter(in, V, ys, z, tid, 1.0f);
    }

    const int c8 = tid & 7;
    const int strip = tid >> 3;          // 0..31, 3 positions each
    const int pos0 = strip * 3;
    const float4* V4 = (const float4*)V;

    for (int r = 0; r < TY; ++r) {
        const int y = y0 + r;
        if (y + BSZ - 1 < DIM) bin_line_scatter(in, V, y + BSZ - 1, z, tid, 1.0f);
        __syncthreads();

        float acc[8];
        #pragma unroll
        for (int k = 0; k < 8; ++k) acc[k] = 0.f;
        #pragma unroll
        for (int d = 0; d < BSZ; ++d) {
            const float4 a = V4[(pos0 + d) * RS4_F + c8 * 2];
            const float4 b = V4[(pos0 + d) * RS4_F + c8 * 2 + 1];
            acc[0] += a.x; acc[1] += a.y; acc[2] += a.z; acc[3] += a.w;
            acc[4] += b.x; acc[5] += b.y; acc[6] += b.z; acc[7] += b.w;
        }
        int pos = pos0;
        #pragma unroll
        for (int j = 0; j < 3; ++j) {
            half8 o;
            #pragma unroll
            for (int k = 0; k < 8; ++k) o[k] = (half_t)acc[k];
            *(half8*)(ws1 + (((size_t)(z * DIM + y) * DIM + pos) * NBINS + c8 * 8)) = o;
            if (j < 2) {
                const float4 a0 = V4[pos * RS4_F + c8 * 2];
                const float4 b0 = V4[pos * RS4_F + c8 * 2 + 1];
                const float4 a1 = V4[(pos + BSZ) * RS4_F + c8 * 2];
                const float4 b1 = V4[(pos + BSZ) * RS4_F + c8 * 2 + 1];
                acc[0] += a1.x - a0.x; acc[1] += a1.y - a0.y;
                acc[2] += a1.z - a0.z; acc[3] += a1.w - a0.w;
                acc[4] += b1.x - b0.x; acc[5] += b1.y - b0.y;
                acc[6] += b1.z - b0.z; acc[7] += b1.w - b0.w;
                ++pos;
            }
        }
        __syncthreads();
        if (r < TY - 1)
            bin_line_scatter(in, V, y, z, tid, -1.0f);
    }
}

// ===========================================================================
// K3S: z-window, fp16 ws1 -> f32 out, pure contiguous streaming.
// Block = (y, z-tile of TZ). Chunked ownership: chunk c in {0,1,2}, thread t
// owns elements c*2048 + t*8 of every (z,y) row -> every half8 load is a
// wave-contiguous 1KB segment; every f32 store wave-contiguous 2KB.
// Running window in 24 f32 registers. No LDS, no barriers.
// ===========================================================================
__global__ __launch_bounds__(NTHREADS) void k3_zstream_h(
    const half_t* __restrict__ ws1, float* __restrict__ out)
{
    const int tid = threadIdx.x;
    const int y  = blockIdx.x;
    const int z0 = blockIdx.y * TZ;
    const int e0 = tid * 8;              // element offset within a 2048-chunk

    float acc[3][8];
    #pragma unroll
    for (int c = 0; c < 3; ++c)
        #pragma unroll
        for (int e = 0; e < 8; ++e) acc[c][e] = 0.f;

    // prologue: rows z0..z0+13 (guarded: z0=84 -> up to 97)
    #pragma unroll
    for (int d = 0; d < BSZ - 1; ++d) {
        const int zz = z0 + d;
        if (zz < DIM) {
            const half_t* p = ws1 + (size_t)(zz * DIM + y) * ROWE + e0;
            #pragma unroll
            for (int c = 0; c < 3; ++c) {
                const half8 h = *(const half8*)(p + c * 2048);
                #pragma unroll
                for (int e = 0; e < 8; ++e) acc[c][e] += (float)h[e];
            }
        }
    }

    for (int i = 0; i < TZ; ++i) {
        const int z = z0 + i;
        if (z + BSZ - 1 < DIM) {
            const half_t* p = ws1 + (size_t)((z + BSZ - 1) * DIM + y) * ROWE + e0;
            #pragma unroll
            for (int c = 0; c < 3; ++c) {
                const half8 h = *(const half8*)(p + c * 2048);
                #pragma unroll
                for (int e = 0; e < 8; ++e) acc[c][e] += (float)h[e];
            }
        }
        float* op = out + (size_t)(z * DIM + y) * ROWE + e0;
        #pragma unroll
        for (int c = 0; c < 3; ++c) {
            float4* o4 = (float4*)(op + c * 2048);
            o4[0] = make_float4(acc[c][0], acc[c][1], acc[c][2], acc[c][3]);
            o4[1] = make_float4(acc[c][4], acc[c][5], acc[c][6], acc[c][7]);
        }
        if (i < TZ - 1) {
            const half_t* p = ws1 + (size_t)(z * DIM + y) * ROWE + e0;   // L2-warm
            #pragma unroll
            for (int c = 0; c < 3; ++c) {
                const half8 h = *(const half8*)(p + c * 2048);
                #pragma unroll
                for (int e = 0; e < 8; ++e) acc[c][e] -= (float)h[e];
            }
        }
    }
}

// ===========================================================================
// Fallback (ws too small): R3/R6 f32 path, in place on out.
// ===========================================================================
__global__ __launch_bounds__(NTHREADS) void k1_bin_xsum_f(
    const float* __restrict__ in, float* __restrict__ out)
{
    __shared__ float V[PADROWS * RS_F];
    const int tid = threadIdx.x;
    const int y = blockIdx.x, z = blockIdx.y;

    for (int i = tid; i < PADROWS * RS4_F; i += NTHREADS)
        ((float4*)V)[i] = make_float4(0.f, 0.f, 0.f, 0.f);
    __syncthreads();
    bin_line_scatter(in, V, y, z, tid, 1.0f);
    __syncthreads();

    const int c4 = tid & 15;
    const int strip = tid >> 4;
    int pos = strip * 6;
    const float4* V4 = (const float4*)V;

    float4 s = make_float4(0.f, 0.f, 0.f, 0.f);
    #pragma unroll
    for (int d = 0; d < BSZ; ++d) {
        const float4 v = V4[(pos + d) * RS4_F + c4];
        s.x += v.x; s.y += v.y; s.z += v.z; s.w += v.w;
    }
    float4* out4 = (float4*)out;
    const int base = (z * DIM + y) * DIM * 16;
    out4[base + pos * 16 + c4] = s;
    #pragma unroll
    for (int j = 1; j < 6; ++j) {
        const float4 a = V4[pos * RS4_F + c4];
        const float4 b = V4[(pos + BSZ) * RS4_F + c4];
        s.x += b.x - a.x; s.y += b.y - a.y; s.z += b.z - a.z; s.w += b.w - a.w;
        ++pos;
        out4[base + pos * 16 + c4] = s;
    }
}

__global__ __launch_bounds__(NTHREADS) void k_axis_sum_f(
    float* __restrict__ data, const int mulY, const int stride4)
{
    __shared__ float4 V4[PADROWS * RS4_F];
    const int tid = threadIdx.x;
    const int base4 = (blockIdx.y * mulY + blockIdx.x) * 16;
    float4* data4 = (float4*)data;

    for (int i = tid; i < DIM * 16; i += NTHREADS) {
        const int pos = i >> 4, c4 = i & 15;
        V4[pos * RS4_F + c4] = data4[base4 + (size_t)pos * stride4 + c4];
    }
    for (int i = tid; i < (PADROWS - DIM) * 16; i += NTHREADS) {
        const int pos = DIM + (i >> 4), c4 = i & 15;
        V4[pos * RS4_F + c4] = make_float4(0.f, 0.f, 0.f, 0.f);
    }
    __syncthreads();

    const int c4 = tid & 15;
    const int strip = tid >> 4;
    int pos = strip * 6;

    float4 s = make_float4(0.f, 0.f, 0.f, 0.f);
    #pragma unroll
    for (int d = 0; d < BSZ; ++d) {
        const float4 v = V4[(pos + d) * RS4_F + c4];
        s.x += v.x; s.y += v.y; s.z += v.z; s.w += v.w;
    }
    data4[base4 + (size_t)pos * stride4 + c4] = s;
    #pragma unroll
    for (int j = 1; j < 6; ++j) {
        const float4 a = V4[pos * RS4_F + c4];
        const float4 b = V4[(pos + BSZ) * RS4_F + c4];
        s.x += b.x - a.x; s.y += b.y - a.y; s.z += b.z - a.z; s.w += b.w - a.w;
        ++pos;
        data4[base4 + (size_t)pos * stride4 + c4] = s;
    }
}

extern "C" void kernel_launch(void* const* d_in, const int* in_sizes, int n_in,
                              void* d_out, int out_size, void* d_ws, size_t ws_size,
                              hipStream_t stream) {
    (void)in_sizes; (void)n_in; (void)out_size;
    const float* x = (const float*)d_in[0];
    float* out = (float*)d_out;
    const size_t nvox = (size_t)DIM * DIM * DIM * NBINS;   // 56,623,104
    const size_t need = nvox * sizeof(half_t);             // 113.2 MB

    dim3 block(NTHREADS);
    if (ws_size >= need) {
        half_t* ws1 = (half_t*)d_ws;
        kA_bin_xy_h<<<dim3(YTILES, DIM), block, 0, stream>>>(x, ws1);
        k3_zstream_h<<<dim3(DIM, ZTILES), block, 0, stream>>>(ws1, out);
    } else {
        k1_bin_xsum_f<<<dim3(DIM, DIM), block, 0, stream>>>(x, out);
        k_axis_sum_f<<<dim3(DIM, DIM), block, 0, stream>>>(out, DIM * DIM * 16, DIM * 16);
        k_axis_sum_f<<<dim3(DIM, DIM), block, 0, stream>>>(out, DIM * 16, DIM * DIM * 16);
    }
}

// Round 12
// 341.018 us; speedup vs baseline: 1.1359x; 1.0021x over previous
//
#include <hip/hip_runtime.h>

typedef _Float16 half_t;
typedef __attribute__((ext_vector_type(8))) _Float16 half8;
typedef __attribute__((ext_vector_type(4))) float f32x4;

#define DIM 96
#define NBINS 64
#define BSZ 15
#define PADROWS (DIM + BSZ - 1)   /* 110 */
#define NTHREADS 256
#define RS_F 68                   /* f32 LDS row stride in floats (64+4 pad) */
#define RS4_F 17                  /* same, in float4 */
#define TY 6                      /* out rows per block in fused kernel */
#define YTILES (DIM / TY)         /* 16 */
#define TZ 16                     /* z rows per block in z-stream kernel */
#define ZTILES (DIM / TZ)         /* 6 */
#define ROWE (DIM * NBINS)        /* 6144 elements per (z,y) row */

// ===========================================================================
// Gradient + faithful soft-binning of voxel (z,y,x) scatter-added (sgn=+1)
// or -subtracted (sgn=-1) into LDS row V[x*RS_F + bin]. Lane x touches ONLY
// row x -> race-free, no barrier needed for the scatter itself.
// ===========================================================================
__device__ __forceinline__ void bin_line_scatter(
    const float* __restrict__ in, float* __restrict__ V,
    const int y, const int z, const int x, const float sgn)
{
    if (x < DIM) {
        const int idx = (z * DIM + y) * DIM + x;
        const float xm = (x > 0)       ? in[idx - 1]         : 0.0f;
        const float xp = (x < DIM - 1) ? in[idx + 1]         : 0.0f;
        const float ym = (y > 0)       ? in[idx - DIM]       : 0.0f;
        const float yp = (y < DIM - 1) ? in[idx + DIM]       : 0.0f;
        const float zm = (z > 0)       ? in[idx - DIM * DIM] : 0.0f;
        const float zp = (z < DIM - 1) ? in[idx + DIM * DIM] : 0.0f;
        const float gx = xp - xm, gy = yp - ym, gz = zp - zm;

        const float EPSF  = 2.220446049250313e-16f;
        const float TWOPI = 6.28318530717958647692f;
        const float PIF   = 3.14159265358979323846f;

        const float r = sqrtf(gx * gx + gy * gy + gz * gz);
        float theta = atanf(gy / (gx + EPSF));
        const float phi = acosf(gz / (r + EPSF));
        if (theta < 0.0f) theta += TWOPI;
        const float t_raw = theta / (TWOPI / 8.0f);
        const float p_raw = phi   / (PIF   / 8.0f);
        const float ft = floorf(t_raw);
        const float fp = floorf(p_raw);
        int lt = (int)ft; if (lt == 8) lt = 0;
        int lp = (int)fp; if (lp == 8) lp = 0;
        const int ht = (lt + 1) & 7;
        const int hp = (lp + 1) & 7;
        const float frac  = t_raw - ft;
        const float w_lo  = fminf(frac, 1.0f - frac);
        const float w_hi  = 1.0f - w_lo;
        const float wp_lo = (frac == 0.0f) ? 1.0f : w_lo;  // faithful: theta frac gates phi split
        const float wp_hi = 1.0f - wp_lo;

        const float rs = r * sgn;
        float* vrow = V + x * RS_F;
        vrow[lt * 8 + lp] += rs * w_lo * wp_lo;
        vrow[ht * 8 + lp] += rs * w_hi * wp_lo;
        vrow[lt * 8 + hp] += rs * w_lo * wp_hi;
        vrow[ht * 8 + hp] += rs * w_hi * wp_hi;
    }
}

// ===========================================================================
// KA: fused bin + x-window + y-window -> fp16 ws1[z][y][x][64].
// Single accumulator plane, sliding y-window via recomputed +/- scatter.
// TY=6: 25 line-bins per 6 output rows (4.17/row).
// ===========================================================================
__global__ __launch_bounds__(NTHREADS) void kA_bin_xy_h(
    const float* __restrict__ in, half_t* __restrict__ ws1)
{
    __shared__ float V[PADROWS * RS_F];
    const int tid = threadIdx.x;
    const int y0 = blockIdx.x * TY;
    const int z  = blockIdx.y;

    for (int i = tid; i < PADROWS * RS4_F; i += NTHREADS)
        ((float4*)V)[i] = make_float4(0.f, 0.f, 0.f, 0.f);
    __syncthreads();

    #pragma unroll
    for (int j = 0; j < BSZ - 1; ++j) {
        const int ys = y0 + j;
        if (ys < DIM) bin_line_scatter(in, V, ys, z, tid, 1.0f);
    }

    const int c8 = tid & 7;
    const int strip = tid >> 3;          // 0..31, 3 positions each
    const int pos0 = strip * 3;
    const float4* V4 = (const float4*)V;

    for (int r = 0; r < TY; ++r) {
        const int y = y0 + r;
        if (y + BSZ - 1 < DIM) bin_line_scatter(in, V, y + BSZ - 1, z, tid, 1.0f);
        __syncthreads();

        float acc[8];
        #pragma unroll
        for (int k = 0; k < 8; ++k) acc[k] = 0.f;
        #pragma unroll
        for (int d = 0; d < BSZ; ++d) {
            const float4 a = V4[(pos0 + d) * RS4_F + c8 * 2];
            const float4 b = V4[(pos0 + d) * RS4_F + c8 * 2 + 1];
            acc[0] += a.x; acc[1] += a.y; acc[2] += a.z; acc[3] += a.w;
            acc[4] += b.x; acc[5] += b.y; acc[6] += b.z; acc[7] += b.w;
        }
        int pos = pos0;
        #pragma unroll
        for (int j = 0; j < 3; ++j) {
            half8 o;
            #pragma unroll
            for (int k = 0; k < 8; ++k) o[k] = (half_t)acc[k];
            *(half8*)(ws1 + (((size_t)(z * DIM + y) * DIM + pos) * NBINS + c8 * 8)) = o;
            if (j < 2) {
                const float4 a0 = V4[pos * RS4_F + c8 * 2];
                const float4 b0 = V4[pos * RS4_F + c8 * 2 + 1];
                const float4 a1 = V4[(pos + BSZ) * RS4_F + c8 * 2];
                const float4 b1 = V4[(pos + BSZ) * RS4_F + c8 * 2 + 1];
                acc[0] += a1.x - a0.x; acc[1] += a1.y - a0.y;
                acc[2] += a1.z - a0.z; acc[3] += a1.w - a0.w;
                acc[4] += b1.x - b0.x; acc[5] += b1.y - b0.y;
                acc[6] += b1.z - b0.z; acc[7] += b1.w - b0.w;
                ++pos;
            }
        }
        __syncthreads();
        if (r < TY - 1)
            bin_line_scatter(in, V, y, z, tid, -1.0f);
    }
}

// ===========================================================================
// K3S: z-window, fp16 ws1 -> f32 out, pure contiguous streaming.
// Block = (y, z-tile of TZ=16). Chunked ownership: chunk c in {0,1,2},
// thread t owns elements c*2048 + t*8 of every (z,y) row -> every half8
// load is a wave-contiguous 1KB segment; every f32 store wave-contiguous
// 2KB, issued NONTEMPORAL (write-once stream, skip L2 pollution).
// Running window in 24 f32 registers. No LDS, no barriers.
// ===========================================================================
__global__ __launch_bounds__(NTHREADS) void k3_zstream_h(
    const half_t* __restrict__ ws1, float* __restrict__ out)
{
    const int tid = threadIdx.x;
    const int y  = blockIdx.x;
    const int z0 = blockIdx.y * TZ;
    const int e0 = tid * 8;              // element offset within a 2048-chunk

    float acc[3][8];
    #pragma unroll
    for (int c = 0; c < 3; ++c)
        #pragma unroll
        for (int e = 0; e < 8; ++e) acc[c][e] = 0.f;

    // prologue: rows z0..z0+13 (z0 <= 80 -> max row 93, no guard needed)
    #pragma unroll
    for (int d = 0; d < BSZ - 1; ++d) {
        const int zz = z0 + d;
        const half_t* p = ws1 + (size_t)(zz * DIM + y) * ROWE + e0;
        #pragma unroll
        for (int c = 0; c < 3; ++c) {
            const half8 h = *(const half8*)(p + c * 2048);
            #pragma unroll
            for (int e = 0; e < 8; ++e) acc[c][e] += (float)h[e];
        }
    }

    #pragma unroll 2
    for (int i = 0; i < TZ; ++i) {
        const int z = z0 + i;
        if (z + BSZ - 1 < DIM) {
            const half_t* p = ws1 + (size_t)((z + BSZ - 1) * DIM + y) * ROWE + e0;
            #pragma unroll
            for (int c = 0; c < 3; ++c) {
                const half8 h = *(const half8*)(p + c * 2048);
                #pragma unroll
                for (int e = 0; e < 8; ++e) acc[c][e] += (float)h[e];
            }
        }
        float* op = out + (size_t)(z * DIM + y) * ROWE + e0;
        #pragma unroll
        for (int c = 0; c < 3; ++c) {
            f32x4* o4 = (f32x4*)(op + c * 2048);
            f32x4 v0 = { acc[c][0], acc[c][1], acc[c][2], acc[c][3] };
            f32x4 v1 = { acc[c][4], acc[c][5], acc[c][6], acc[c][7] };
            __builtin_nontemporal_store(v0, o4);
            __builtin_nontemporal_store(v1, o4 + 1);
        }
        if (i < TZ - 1) {
            const half_t* p = ws1 + (size_t)(z * DIM + y) * ROWE + e0;   // L2-warm
            #pragma unroll
            for (int c = 0; c < 3; ++c) {
                const half8 h = *(const half8*)(p + c * 2048);
                #pragma unroll
                for (int e = 0; e < 8; ++e) acc[c][e] -= (float)h[e];
            }
        }
    }
}

// ===========================================================================
// Fallback (ws too small): R3/R6 f32 path, in place on out.
// ===========================================================================
__global__ __launch_bounds__(NTHREADS) void k1_bin_xsum_f(
    const float* __restrict__ in, float* __restrict__ out)
{
    __shared__ float V[PADROWS * RS_F];
    const int tid = threadIdx.x;
    const int y = blockIdx.x, z = blockIdx.y;

    for (int i = tid; i < PADROWS * RS4_F; i += NTHREADS)
        ((float4*)V)[i] = make_float4(0.f, 0.f, 0.f, 0.f);
    __syncthreads();
    bin_line_scatter(in, V, y, z, tid, 1.0f);
    __syncthreads();

    const int c4 = tid & 15;
    const int strip = tid >> 4;
    int pos = strip * 6;
    const float4* V4 = (const float4*)V;

    float4 s = make_float4(0.f, 0.f, 0.f, 0.f);
    #pragma unroll
    for (int d = 0; d < BSZ; ++d) {
        const float4 v = V4[(pos + d) * RS4_F + c4];
        s.x += v.x; s.y += v.y; s.z += v.z; s.w += v.w;
    }
    float4* out4 = (float4*)out;
    const int base = (z * DIM + y) * DIM * 16;
    out4[base + pos * 16 + c4] = s;
    #pragma unroll
    for (int j = 1; j < 6; ++j) {
        const float4 a = V4[pos * RS4_F + c4];
        const float4 b = V4[(pos + BSZ) * RS4_F + c4];
        s.x += b.x - a.x; s.y += b.y - a.y; s.z += b.z - a.z; s.w += b.w - a.w;
        ++pos;
        out4[base + pos * 16 + c4] = s;
    }
}

__global__ __launch_bounds__(NTHREADS) void k_axis_sum_f(
    float* __restrict__ data, const int mulY, const int stride4)
{
    __shared__ float4 V4[PADROWS * RS4_F];
    const int tid = threadIdx.x;
    const int base4 = (blockIdx.y * mulY + blockIdx.x) * 16;
    float4* data4 = (float4*)data;

    for (int i = tid; i < DIM * 16; i += NTHREADS) {
        const int pos = i >> 4, c4 = i & 15;
        V4[pos * RS4_F + c4] = data4[base4 + (size_t)pos * stride4 + c4];
    }
    for (int i = tid; i < (PADROWS - DIM) * 16; i += NTHREADS) {
        const int pos = DIM + (i >> 4), c4 = i & 15;
        V4[pos * RS4_F + c4] = make_float4(0.f, 0.f, 0.f, 0.f);
    }
    __syncthreads();

    const int c4 = tid & 15;
    const int strip = tid >> 4;
    int pos = strip * 6;

    float4 s = make_float4(0.f, 0.f, 0.f, 0.f);
    #pragma unroll
    for (int d = 0; d < BSZ; ++d) {
        const float4 v = V4[(pos + d) * RS4_F + c4];
        s.x += v.x; s.y += v.y; s.z += v.z; s.w += v.w;
    }
    data4[base4 + (size_t)pos * stride4 + c4] = s;
    #pragma unroll
    for (int j = 1; j < 6; ++j) {
        const float4 a = V4[pos * RS4_F + c4];
        const float4 b = V4[(pos + BSZ) * RS4_F + c4];
        s.x += b.x - a.x; s.y += b.y - a.y; s.z += b.z - a.z; s.w += b.w - a.w;
        ++pos;
        data4[base4 + (size_t)pos * stride4 + c4] = s;
    }
}

extern "C" void kernel_launch(void* const* d_in, const int* in_sizes, int n_in,
                              void* d_out, int out_size, void* d_ws, size_t ws_size,
                              hipStream_t stream) {
    (void)in_sizes; (void)n_in; (void)out_size;
    const float* x = (const float*)d_in[0];
    float* out = (float*)d_out;
    const size_t nvox = (size_t)DIM * DIM * DIM * NBINS;   // 56,623,104
    const size_t need = nvox * sizeof(half_t);             // 113.2 MB

    dim3 block(NTHREADS);
    if (ws_size >= need) {
        half_t* ws1 = (half_t*)d_ws;
        kA_bin_xy_h<<<dim3(YTILES, DIM), block, 0, stream>>>(x, ws1);
        k3_zstream_h<<<dim3(DIM, ZTILES), block, 0, stream>>>(ws1, out);
    } else {
        k1_bin_xsum_f<<<dim3(DIM, DIM), block, 0, stream>>>(x, out);
        k_axis_sum_f<<<dim3(DIM, DIM), block, 0, stream>>>(out, DIM * DIM * 16, DIM * 16);
        k_axis_sum_f<<<dim3(DIM, DIM), block, 0, stream>>>(out, DIM * 16, DIM * DIM * 16);
    }
}